// Round 4
// baseline (117.588 us; speedup 1.0000x reference)
//
#include <hip/hip_runtime.h>

// ARIMA(2,1,2) residual recurrence, coalesced LDS-transpose tiles + prefetch.
//
// eps_j = (y[j+3]-y[j+2]-mu-phi0*y[j+2]-phi1*y[j+1]) - th0*eps_{j-1} - th1*eps_{j-2}
// out[b, 0..4092] = eps, out[b, 4093..4094] = 0.
//
// Decomposition: 1 block = 1 wave = 64 rows x one 128-output chunk, warm-up 61
// steps from zero state (linear recurrence; initial-state error ~rho^61 is
// negligible — R1/R2 absmax 0.0156 is pure bf16 rounding).
//
// R4 fix vs R3: tail clamp in stage() must be DESTINATION-corrected. Last
// chunk's last tile (tb=4067) clamps lane scol=28 from off=4095 to 4092; the
// staged float4 must land at lds cols 25..28 (sdcol = off - tbase), not 28..31,
// so col 28 = y[4095] feeds output j=4092 correctly.

#define TSEQ   4096
#define TOUT   4095
#define NJ     4093
#define CHUNK  128
#define NCHUNK 32
#define WARM   61      // tile0 yields 29 outputs; 29 + 5*32 = 189 = WARM+CHUNK
#define TILE   32
#define PITCH  65

__global__ __launch_bounds__(64, 4) void arima_eps_tiled(
    const float* __restrict__ y,
    const float* __restrict__ phi,
    const float* __restrict__ theta,
    const float* __restrict__ mu,
    float* __restrict__ out, int B)
{
    __shared__ float lds[TILE][PITCH];   // [local col][row(=lane)], 2-way banks

    const int lane = threadIdx.x;
    const int g = blockIdx.x >> 5;       // row group (64 rows)
    const int c = blockIdx.x & (NCHUNK - 1);
    const int rowbase = g * 64;
    (void)B;

    const float p0 = phi[0], p1 = phi[1];
    const float q0 = theta[0], q1 = theta[1];
    const float m  = mu[0];

    const float* __restrict__ Y = y + (size_t)rowbase * TSEQ;
    float* __restrict__ O       = out + (size_t)rowbase * TOUT;

    const int j0 = c * CHUNK;
    const int j1 = min(j0 + CHUNK, NJ);
    const int jw = max(j0 - WARM, 0);

    const int srow = lane >> 3;          // 0..7 row offset
    const int scol = (lane & 7) << 2;    // 0,4,..,28 col base

    float4 stg[8];
    int sdcol;                           // lds col base for staged data

    // issue 8 coalesced float4 loads (cols tbase..tbase+31 of 64 rows) to regs
    auto stage = [&](int tbase) {
        int off = tbase + scol;
        if (off > TSEQ - 4) off = TSEQ - 4;   // tail clamp (last chunk only)
        sdcol = off - tbase;                  // destination-corrected col base
        #pragma unroll
        for (int qq = 0; qq < 8; ++qq) {
            const int r = qq * 8 + srow;
            stg[qq] = *reinterpret_cast<const float4*>(&Y[(size_t)r * TSEQ + off]);
        }
    };
    // regs -> LDS transposed (clamped lanes overlap-write identical values)
    auto lds_write = [&]() {
        #pragma unroll
        for (int qq = 0; qq < 8; ++qq) {
            const int r = qq * 8 + srow;
            lds[sdcol + 0][r] = stg[qq].x;
            lds[sdcol + 1][r] = stg[qq].y;
            lds[sdcol + 2][r] = stg[qq].z;
            lds[sdcol + 3][r] = stg[qq].w;
        }
    };

    float a, b, e1 = 0.f, e2 = 0.f;

    // 8 batched LDS reads -> 8 recurrence steps -> 8 in-place eps writes
    auto step8 = [&](int cb) {
        float yv[8], ev[8];
        #pragma unroll
        for (int k = 0; k < 8; ++k) yv[k] = lds[cb + k][lane];
        #pragma unroll
        for (int k = 0; k < 8; ++k) {
            const float cc  = yv[k];
            const float tgt = cc - b - m - p0 * b - p1 * a;
            const float e   = tgt - q0 * e1 - q1 * e2;
            ev[k] = e;
            e2 = e1; e1 = e; a = b; b = cc;
        }
        #pragma unroll
        for (int k = 0; k < 8; ++k) lds[cb + k][lane] = ev[k];
    };

    // coalesced dump of output cols [max(jt,j0), min(jcur,j1)) from LDS
    auto dump = [&](int jt, int jcur, int tb) {
        const int jd  = max(jt, j0);
        const int je  = min(jcur, j1);
        const int cnt = je - jd;
        if (cnt <= 0) return;
        const int dcol = jd + 3 - tb;
        const int col  = lane & 31;
        const int rh   = lane >> 5;
        const bool on  = col < cnt;
        #pragma unroll
        for (int r2 = 0; r2 < 32; ++r2) {
            const int r = r2 * 2 + rh;
            if (on) O[(size_t)r * TOUT + jd + col] = lds[dcol + col][r];
        }
    };

    // ---- tile 0: cols jw..jw+31; a,b from cols jw+1, jw+2 ----
    int tb = jw;
    stage(tb);
    lds_write();
    __syncthreads();
    {
        float yv[8], ev[5];
        #pragma unroll
        for (int k = 0; k < 8; ++k) yv[k] = lds[k][lane];
        a = yv[1]; b = yv[2];            // zero initial eps state
        #pragma unroll
        for (int k = 3; k < 8; ++k) {
            const float cc  = yv[k];
            const float tgt = cc - b - m - p0 * b - p1 * a;
            const float e   = tgt - q0 * e1 - q1 * e2;
            ev[k - 3] = e;
            e2 = e1; e1 = e; a = b; b = cc;
        }
        #pragma unroll
        for (int k = 3; k < 8; ++k) lds[k][lane] = ev[k - 3];
    }
    step8(8); step8(16); step8(24);
    int jt = jw;
    int j  = jw + TILE - 3;              // 29 outputs

    for (;;) {
        const bool more = (j < j1);
        if (more) stage(tb + TILE);      // prefetch next tile (issue early)
        dump(jt, j, tb);                 // drain current tile from LDS
        if (!more) break;
        __syncthreads();                 // dump reads done before overwrite
        lds_write();                     // write late (waits vmcnt on stg use)
        __syncthreads();
        tb += TILE;
        jt = tb - 3;
        step8(0); step8(8); step8(16); step8(24);
        j = jt + TILE;
    }

    // trailing Q zeros (harness poisons d_out)
    if (c == NCHUNK - 1) {
        O[(size_t)lane * TOUT + NJ]     = 0.f;
        O[(size_t)lane * TOUT + NJ + 1] = 0.f;
    }
}

extern "C" void kernel_launch(void* const* d_in, const int* in_sizes, int n_in,
                              void* d_out, int out_size, void* d_ws, size_t ws_size,
                              hipStream_t stream) {
    const float* y     = (const float*)d_in[0];
    const float* phi   = (const float*)d_in[1];
    const float* theta = (const float*)d_in[2];
    const float* mu    = (const float*)d_in[3];
    float* out         = (float*)d_out;

    int B = in_sizes[0] / TSEQ;                 // 8192
    int rowgroups = B / 64;                     // 128
    dim3 block(64);
    dim3 grid(rowgroups * NCHUNK);              // 4096 single-wave blocks
    arima_eps_tiled<<<grid, block, 0, stream>>>(y, phi, theta, mu, out, B);
}

// Round 5
// 68.168 us; speedup vs baseline: 1.7250x; 1.7250x over previous
//
#include <hip/hip_runtime.h>

// ARIMA(2,1,2) residual recurrence — single-wave blocks, fence-only sync.
//
// eps_j = (y[j+3]-y[j+2]-mu-phi0*y[j+2]-phi1*y[j+1]) - q0*eps_{j-1} - q1*eps_{j-2}
// out[b,0..4092] = eps, out[b,4093..4094] = 0.
//
// R5 vs R2/R4: blocks are ONE wave, so __syncthreads (which forces a full
// vmcnt(0) drain before s_barrier) is replaced by a pure LDS fence
// (s_waitcnt lgkmcnt(0) + sched_barrier). Prefetch loads and dump stores now
// stay in flight across tiles -> MLP builds -> effective HBM BW rises.
// Geometry: CHUNK=256 (low warm-up amp), TILE=64, WARM=61 => exactly 5 tiles
// per chunk. Composed 2-step eps chain (4x shorter serial latency):
//   e[k] = (tg[k]-q0*tg[k-1]) + (q0^2-q1)*e[k-2] + (q0*q1)*e[k-3].

#define TSEQ   4096
#define TOUT   4095
#define NJ     4093
#define CHUNK  256
#define NCHUNK 16
#define TILE   64
#define PITCH  65
#define WARM   61

// cross-lane LDS fence for a single-wave block: lanes are lockstep, so only
// DS completion ordering is needed — no s_barrier, no vmcnt drain.
#define LGKM_FENCE() do { \
    asm volatile("s_waitcnt lgkmcnt(0)" ::: "memory"); \
    __builtin_amdgcn_sched_barrier(0); \
} while (0)

__global__ __launch_bounds__(64) void arima_eps_sw(
    const float* __restrict__ y,
    const float* __restrict__ phi,
    const float* __restrict__ theta,
    const float* __restrict__ mu,
    float* __restrict__ out)
{
    __shared__ float lds[TILE][PITCH];   // [col][row(=lane)], 2-way banks=free

    const int lane = threadIdx.x;
    const int g = blockIdx.x >> 4;       // 64-row group
    const int c = blockIdx.x & (NCHUNK - 1);
    const int rowbase = g * 64;

    const float p0 = phi[0], p1v = phi[1];
    const float q0 = theta[0], q1 = theta[1];
    const float m  = mu[0];
    const float c1 = 1.0f + p0;          // tg = y[j+3] - c1*y[j+2] - p1*y[j+1] - m
    const float A  = q0 * q0 - q1;       // composed-chain coefficients
    const float Bc = q0 * q1;

    const float* __restrict__ Y = y + (size_t)rowbase * TSEQ;
    float* __restrict__ O       = out + (size_t)rowbase * TOUT;

    const int j0 = c * CHUNK;
    const int j1 = min(j0 + CHUNK, NJ);
    const int jw = max(j0 - WARM, 0);

    const int srow = lane >> 4;          // 0..3
    const int scol = (lane & 15) << 2;   // 0,4,...,60

    float4 stg[16];
    int sdcol;

    // issue 16 coalesced float4 loads (64 rows x cols tbase..tbase+63) to regs
    auto stage = [&](int tbase) {
        int off = tbase + scol;
        if (off > TSEQ - 4) off = TSEQ - 4;   // tail clamp (c==15 last tile)
        sdcol = off - tbase;                  // destination-corrected col
        #pragma unroll
        for (int qq = 0; qq < 16; ++qq) {
            const int r = qq * 4 + srow;
            stg[qq] = *reinterpret_cast<const float4*>(&Y[(size_t)r * TSEQ + off]);
        }
    };
    auto lds_write = [&]() {             // compiler auto-waits counted vmcnt
        #pragma unroll
        for (int qq = 0; qq < 16; ++qq) {
            const int r = qq * 4 + srow;
            lds[sdcol + 0][r] = stg[qq].x;
            lds[sdcol + 1][r] = stg[qq].y;
            lds[sdcol + 2][r] = stg[qq].z;
            lds[sdcol + 3][r] = stg[qq].w;
        }
    };

    // recurrence state
    float yp1, yp2;                      // y[j+2], y[j+1] history
    float e1 = 0.f, e2 = 0.f, e3 = 0.f;  // eps history
    float tp = 0.f;                      // previous tg

    // 8 composed steps: lds cols cb..cb+7 (y) -> eps written in place
    auto step8 = [&](int cb) {
        float yv[8];
        #pragma unroll
        for (int k = 0; k < 8; ++k) yv[k] = lds[cb + k][lane];
        float tg[8];
        {
            float pa = yp2, pb = yp1;
            #pragma unroll
            for (int k = 0; k < 8; ++k) {
                float t = __builtin_fmaf(-c1, pb, yv[k]);
                t = __builtin_fmaf(-p1v, pa, t);
                tg[k] = t - m;
                pa = pb; pb = yv[k];
            }
        }
        yp2 = yv[6]; yp1 = yv[7];
        float T[8];
        T[0] = __builtin_fmaf(-q0, tp, tg[0]);
        #pragma unroll
        for (int k = 1; k < 8; ++k) T[k] = __builtin_fmaf(-q0, tg[k - 1], tg[k]);
        tp = tg[7];
        float ev[8];
        ev[0] = __builtin_fmaf(A, e2,    __builtin_fmaf(Bc, e3,    T[0]));
        ev[1] = __builtin_fmaf(A, e1,    __builtin_fmaf(Bc, e2,    T[1]));
        ev[2] = __builtin_fmaf(A, ev[0], __builtin_fmaf(Bc, e1,    T[2]));
        ev[3] = __builtin_fmaf(A, ev[1], __builtin_fmaf(Bc, ev[0], T[3]));
        ev[4] = __builtin_fmaf(A, ev[2], __builtin_fmaf(Bc, ev[1], T[4]));
        ev[5] = __builtin_fmaf(A, ev[3], __builtin_fmaf(Bc, ev[2], T[5]));
        ev[6] = __builtin_fmaf(A, ev[4], __builtin_fmaf(Bc, ev[3], T[6]));
        ev[7] = __builtin_fmaf(A, ev[5], __builtin_fmaf(Bc, ev[4], T[7]));
        e3 = ev[5]; e2 = ev[6]; e1 = ev[7];
        #pragma unroll
        for (int k = 0; k < 8; ++k) lds[cb + k][lane] = ev[k];
    };

    // scalar coalesced dump of eps cols [max(jt,j0), min(jcur,j1))
    auto dump = [&](int jt, int jcur, int tb) {
        const int jd  = max(jt, j0);
        const int je  = min(jcur, j1);
        const int cnt = je - jd;
        if (cnt <= 0) return;
        const int dcol = jd + 3 - tb;
        const bool on  = lane < cnt;
        float* op = O + jd + lane;
        #pragma unroll 8
        for (int r = 0; r < 64; ++r) {
            if (on) op[(size_t)r * TOUT] = lds[dcol + lane][r];
        }
    };

    // ---- tile 0: cols jw..jw+63; 5 direct steps then composed ----
    int tb = jw;
    stage(tb);
    lds_write();
    LGKM_FENCE();
    {
        float yv0[8];
        #pragma unroll
        for (int k = 0; k < 8; ++k) yv0[k] = lds[k][lane];
        yp2 = yv0[1]; yp1 = yv0[2];      // y[j+1], y[j+2] for j = tb
        float ev[5];
        #pragma unroll
        for (int k = 3; k < 8; ++k) {    // direct form, seeds composed state
            float t = __builtin_fmaf(-c1, yp1, yv0[k]);
            t = __builtin_fmaf(-p1v, yp2, t);
            t -= m;                      // tg
            float e = __builtin_fmaf(-q0, e1, t);
            e = __builtin_fmaf(-q1, e2, e);
            ev[k - 3] = e;
            e3 = e2; e2 = e1; e1 = e;
            tp = t;
            yp2 = yp1; yp1 = yv0[k];
        }
        #pragma unroll
        for (int k = 3; k < 8; ++k) lds[k][lane] = ev[k - 3];
    }
    step8(8); step8(16); step8(24); step8(32); step8(40); step8(48); step8(56);
    int jt = jw;
    int j  = jw + 61;                    // 61 outputs in tile 0

    for (;;) {
        const bool more = (j < j1);
        if (more) stage(tb + TILE);      // issue next-tile loads (stay in flight)
        LGKM_FENCE();                    // eps writes visible for dump
        dump(jt, j, tb);                 // stores drain lazily (no vmcnt drain)
        if (!more) break;
        LGKM_FENCE();                    // dump reads done before overwrite
        lds_write();                     // waits counted vmcnt (loads only)
        LGKM_FENCE();                    // new y visible
        tb += TILE;
        jt = tb - 3;
        step8(0); step8(8); step8(16); step8(24);
        step8(32); step8(40); step8(48); step8(56);
        j = jt + TILE;
    }

    // trailing Q zeros (harness poisons d_out)
    if (c == NCHUNK - 1) {
        O[(size_t)lane * TOUT + NJ]     = 0.f;
        O[(size_t)lane * TOUT + NJ + 1] = 0.f;
    }
}

extern "C" void kernel_launch(void* const* d_in, const int* in_sizes, int n_in,
                              void* d_out, int out_size, void* d_ws, size_t ws_size,
                              hipStream_t stream) {
    const float* y     = (const float*)d_in[0];
    const float* phi   = (const float*)d_in[1];
    const float* theta = (const float*)d_in[2];
    const float* mu    = (const float*)d_in[3];
    float* out         = (float*)d_out;

    int B = in_sizes[0] / TSEQ;                 // 8192
    int rowgroups = B / 64;                     // 128
    dim3 block(64);
    dim3 grid(rowgroups * NCHUNK);              // 2048 single-wave blocks
    arima_eps_sw<<<grid, block, 0, stream>>>(y, phi, theta, mu, out);
}